// Round 1
// baseline (90.709 us; speedup 1.0000x reference)
//
#include <hip/hip_runtime.h>

typedef unsigned short u16;
typedef short bf16x8 __attribute__((ext_vector_type(8)));
typedef float f32x4 __attribute__((ext_vector_type(4)));

#define AS1 __attribute__((address_space(1)))
#define AS3 __attribute__((address_space(3)))

__device__ __forceinline__ u16 f2bf(float f) {
    unsigned u = __float_as_uint(f);
    u += 0x7fffu + ((u >> 16) & 1u);   // RNE
    return (u16)(u >> 16);
}
__device__ __forceinline__ float bf2f(u16 h) {
    return __uint_as_float(((unsigned)h) << 16);
}

__device__ __forceinline__ void gload_lds16(const void* g, void* l) {
    __builtin_amdgcn_global_load_lds((AS1 unsigned int*)(g),
                                     (AS3 unsigned int*)(l), 16, 0, 0);
}

// ---------------- stage 1: dtype prep ----------------
__global__ void cvt_bf16_kernel(const float* __restrict__ in, u16* __restrict__ out, int n4) {
    int i = blockIdx.x * blockDim.x + threadIdx.x;
    if (i >= n4) return;
    float4 v = reinterpret_cast<const float4*>(in)[i];
    ushort4 o;
    o.x = f2bf(v.x); o.y = f2bf(v.y); o.z = f2bf(v.z); o.w = f2bf(v.w);
    reinterpret_cast<ushort4*>(out)[i] = o;
}

// Qt[n][m] = x[b,m]*emb[m,d],  n = b*16+d   (4096 x 256 bf16)
__global__ void build_qt_kernel(const float* __restrict__ x, const float* __restrict__ emb,
                                u16* __restrict__ Qt) {
    int n = blockIdx.x;           // 0..4095
    int b = n >> 4, d = n & 15;
    int m0 = threadIdx.x * 4;     // 64 threads * 4
    float4 xv = *reinterpret_cast<const float4*>(x + b * 256 + m0);
    ushort4 q;
    q.x = f2bf(xv.x * emb[(m0 + 0) * 16 + d]);
    q.y = f2bf(xv.y * emb[(m0 + 1) * 16 + d]);
    q.z = f2bf(xv.z * emb[(m0 + 2) * 16 + d]);
    q.w = f2bf(xv.w * emb[(m0 + 3) * 16 + d]);
    *reinterpret_cast<ushort4*>(Qt + n * 256 + m0) = q;
}

// ---------------- stage 2: layer 1 (fused GEMM + h-reduction) ----------------
// grid (16 ntiles, 64 o), 512 threads. Tile: 256 h x 256 n, K=256 (m), chunks of 64.
__global__ __launch_bounds__(512, 1) void cin1_kernel(
    const u16* __restrict__ W0b, const u16* __restrict__ Qt,
    const float* __restrict__ b0, u16* __restrict__ Pt, float* __restrict__ S1)
{
    __shared__ __attribute__((aligned(16))) u16 As[2][256 * 64];
    __shared__ __attribute__((aligned(16))) u16 Bs[2][256 * 64];
    __shared__ float part[2][256];

    const int tid = threadIdx.x, lane = tid & 63, w = tid >> 6;
    const int wh = w >> 2, wn = w & 3;
    const int ntile = blockIdx.x, o = blockIdx.y;

    // staging constants: 8 rows/instr, slot swizzle s = p ^ (r&7)
    const int srow = lane >> 3;
    const int sOff = ((lane & 7) ^ srow) * 8;
    const int baseA = (o * 256 + w * 32 + srow) * 256 + sOff;
    const int baseB = (ntile * 256 + w * 32 + srow) * 256 + sOff;
    const int ldsW = w * 2048;

    // fragment-read constants (read logical slot s at physical s ^ (row&7))
    const int swz0 = ((0 + (lane >> 4)) ^ (lane & 7)) * 8;
    const int swz1 = ((4 + (lane >> 4)) ^ (lane & 7)) * 8;
    const int aBase = wh * 8192 + (lane & 15) * 64;
    const int bBase = wn * 4096 + (lane & 15) * 64;

    f32x4 zero = {0.f, 0.f, 0.f, 0.f};
    f32x4 acc[8][4];
#pragma unroll
    for (int f = 0; f < 8; ++f)
#pragma unroll
        for (int g = 0; g < 4; ++g) acc[f][g] = zero;

    auto stage = [&](int kc, int bb) {
#pragma unroll
        for (int i = 0; i < 4; ++i) {
            gload_lds16(W0b + baseA + i * 2048 + kc * 64, &As[bb][ldsW + i * 512]);
            gload_lds16(Qt  + baseB + i * 2048 + kc * 64, &Bs[bb][ldsW + i * 512]);
        }
    };

    stage(0, 0);
    __syncthreads();
    for (int kc = 0; kc < 4; ++kc) {
        const int bb = kc & 1;
        if (kc < 3) stage(kc + 1, bb ^ 1);            // prefetch next chunk
        const u16* Ab = &As[bb][0];
        const u16* Bb = &Bs[bb][0];
#pragma unroll
        for (int ks = 0; ks < 2; ++ks) {
            const int sw = ks ? swz1 : swz0;
            bf16x8 a[8], b[4];
#pragma unroll
            for (int f = 0; f < 8; ++f)
                a[f] = *reinterpret_cast<const bf16x8*>(Ab + aBase + f * 1024 + sw);
#pragma unroll
            for (int g = 0; g < 4; ++g)
                b[g] = *reinterpret_cast<const bf16x8*>(Bb + bBase + g * 1024 + sw);
#pragma unroll
            for (int f = 0; f < 8; ++f)
#pragma unroll
                for (int g = 0; g < 4; ++g)
                    acc[f][g] = __builtin_amdgcn_mfma_f32_16x16x32_bf16(a[f], b[g], acc[f][g], 0, 0, 0);
        }
        __syncthreads();                               // drains prefetch vmcnt + sync bufs
    }

    // epilogue: X1[o][n] = sum_h Q[h][n] * G[h][n]
    float psum[4] = {0.f, 0.f, 0.f, 0.f};
    const int hE = wh * 128 + 4 * (lane >> 4);
#pragma unroll
    for (int g = 0; g < 4; ++g) {
        const int n = ntile * 256 + wn * 64 + g * 16 + (lane & 15);
        const u16* wp = Qt + n * 256 + hE;
#pragma unroll
        for (int f = 0; f < 8; ++f) {
            ushort4 wv = *reinterpret_cast<const ushort4*>(wp + f * 16);
            psum[g] += bf2f(wv.x) * acc[f][g][0] + bf2f(wv.y) * acc[f][g][1]
                     + bf2f(wv.z) * acc[f][g][2] + bf2f(wv.w) * acc[f][g][3];
        }
    }
#pragma unroll
    for (int g = 0; g < 4; ++g) {
        float p = psum[g];
        p += __shfl_xor(p, 16);
        p += __shfl_xor(p, 32);
        if (lane < 16) part[wh][wn * 64 + g * 16 + lane] = p;
    }
    __syncthreads();
    if (tid < 256) {
        const int nl = tid;
        float v = part[0][nl] + part[1][nl] + b0[o];
        float r = fmaxf(v, 0.0f);
        const int n = ntile * 256 + nl;
        if (o < 32) {
            Pt[n * 32 + o] = f2bf(r);                 // Xp for layer 2
        } else {
            float s = r;                               // sum over d (nl&15)
            s += __shfl_xor(s, 1); s += __shfl_xor(s, 2);
            s += __shfl_xor(s, 4); s += __shfl_xor(s, 8);
            if ((nl & 15) == 0) S1[(n >> 4) * 32 + (o - 32)] = s;
        }
    }
}

// ---------------- stage 3: layer 2 ----------------
// grid (16 ntiles, 16 og), 512 threads. Tile: 128 rows (4 o's x 32 h) x 256 n, K=256.
__global__ __launch_bounds__(512, 1) void cin2_kernel(
    const u16* __restrict__ W1b, const u16* __restrict__ Qt,
    const u16* __restrict__ Pt, const float* __restrict__ b1, float* __restrict__ S2)
{
    __shared__ __attribute__((aligned(16))) u16 As[2][128 * 64];
    __shared__ __attribute__((aligned(16))) u16 Bs[2][256 * 64];
    __shared__ float part[2][2][256];

    const int tid = threadIdx.x, lane = tid & 63, w = tid >> 6;
    const int wh = w >> 2, wn = w & 3;
    const int ntile = blockIdx.x, og = blockIdx.y;

    const int srow = lane >> 3;
    const int sOff = ((lane & 7) ^ srow) * 8;
    const int baseA = (og * 128 + w * 16 + srow) * 256 + sOff;
    const int baseB = (ntile * 256 + w * 32 + srow) * 256 + sOff;
    const int ldsWA = w * 1024;
    const int ldsWB = w * 2048;

    const int swz0 = ((0 + (lane >> 4)) ^ (lane & 7)) * 8;
    const int swz1 = ((4 + (lane >> 4)) ^ (lane & 7)) * 8;
    const int aBase = wh * 4096 + (lane & 15) * 64;
    const int bBase = wn * 4096 + (lane & 15) * 64;

    f32x4 zero = {0.f, 0.f, 0.f, 0.f};
    f32x4 acc[4][4];
#pragma unroll
    for (int f = 0; f < 4; ++f)
#pragma unroll
        for (int g = 0; g < 4; ++g) acc[f][g] = zero;

    auto stage = [&](int kc, int bb) {
#pragma unroll
        for (int i = 0; i < 2; ++i)
            gload_lds16(W1b + baseA + i * 2048 + kc * 64, &As[bb][ldsWA + i * 512]);
#pragma unroll
        for (int i = 0; i < 4; ++i)
            gload_lds16(Qt + baseB + i * 2048 + kc * 64, &Bs[bb][ldsWB + i * 512]);
    };

    stage(0, 0);
    __syncthreads();
    for (int kc = 0; kc < 4; ++kc) {
        const int bb = kc & 1;
        if (kc < 3) stage(kc + 1, bb ^ 1);
        const u16* Ab = &As[bb][0];
        const u16* Bb = &Bs[bb][0];
#pragma unroll
        for (int ks = 0; ks < 2; ++ks) {
            const int sw = ks ? swz1 : swz0;
            bf16x8 a[4], b[4];
#pragma unroll
            for (int f = 0; f < 4; ++f)
                a[f] = *reinterpret_cast<const bf16x8*>(Ab + aBase + f * 1024 + sw);
#pragma unroll
            for (int g = 0; g < 4; ++g)
                b[g] = *reinterpret_cast<const bf16x8*>(Bb + bBase + g * 1024 + sw);
#pragma unroll
            for (int f = 0; f < 4; ++f)
#pragma unroll
                for (int g = 0; g < 4; ++g)
                    acc[f][g] = __builtin_amdgcn_mfma_f32_16x16x32_bf16(a[f], b[g], acc[f][g], 0, 0, 0);
        }
        __syncthreads();
    }

    // reduction: rows r = wh*64+f*16+(4*(lane>>4)+e); o_local = 2*wh + (f>>1); h = r&31
    float psum[2][4] = {{0.f,0.f,0.f,0.f},{0.f,0.f,0.f,0.f}};
#pragma unroll
    for (int g = 0; g < 4; ++g) {
        const int n = ntile * 256 + wn * 64 + g * 16 + (lane & 15);
#pragma unroll
        for (int f = 0; f < 4; ++f) {
            const int h = (f & 1) * 16 + 4 * (lane >> 4);
            ushort4 wv = *reinterpret_cast<const ushort4*>(Pt + n * 32 + h);
            psum[f >> 1][g] += bf2f(wv.x) * acc[f][g][0] + bf2f(wv.y) * acc[f][g][1]
                             + bf2f(wv.z) * acc[f][g][2] + bf2f(wv.w) * acc[f][g][3];
        }
    }
#pragma unroll
    for (int ol = 0; ol < 2; ++ol)
#pragma unroll
        for (int g = 0; g < 4; ++g) {
            float p = psum[ol][g];
            p += __shfl_xor(p, 16);
            p += __shfl_xor(p, 32);
            if (lane < 16) part[wh][ol][wn * 64 + g * 16 + lane] = p;
        }
    __syncthreads();
    if (tid < 256) {
        const int nl = tid;
        const int n = ntile * 256 + nl;
#pragma unroll
        for (int ol4 = 0; ol4 < 4; ++ol4) {
            const int o = og * 4 + ol4;
            float v = part[ol4 >> 1][ol4 & 1][nl] + b1[o];
            float r = fmaxf(v, 0.0f);
            float s = r;
            s += __shfl_xor(s, 1); s += __shfl_xor(s, 2);
            s += __shfl_xor(s, 4); s += __shfl_xor(s, 8);
            if ((nl & 15) == 0) S2[(n >> 4) * 64 + o] = s;
        }
    }
}

// ---------------- stage 4: final FC ----------------
__global__ void final_fc_kernel(const float* __restrict__ S1, const float* __restrict__ S2,
                                const float* __restrict__ fcW, const float* __restrict__ fcb,
                                float* __restrict__ out) {
    int b = threadIdx.x;   // 256
    float a0 = fcb[0], a1 = fcb[1];
#pragma unroll 8
    for (int c = 0; c < 32; ++c) {
        float v = S1[b * 32 + c];
        a0 += v * fcW[c]; a1 += v * fcW[96 + c];
    }
#pragma unroll 8
    for (int c = 0; c < 64; ++c) {
        float v = S2[b * 64 + c];
        a0 += v * fcW[32 + c]; a1 += v * fcW[96 + 32 + c];
    }
    out[b * 2 + 0] = a0;
    out[b * 2 + 1] = a1;
}

extern "C" void kernel_launch(void* const* d_in, const int* in_sizes, int n_in,
                              void* d_out, int out_size, void* d_ws, size_t ws_size,
                              hipStream_t stream) {
    const float* x   = (const float*)d_in[0];
    const float* emb = (const float*)d_in[1];
    const float* W0  = (const float*)d_in[2];
    const float* b0  = (const float*)d_in[3];
    const float* W1  = (const float*)d_in[4];
    const float* b1  = (const float*)d_in[5];
    const float* fcW = (const float*)d_in[6];
    const float* fcb = (const float*)d_in[7];
    float* out = (float*)d_out;

    char* ws = (char*)d_ws;
    u16*   W0b = (u16*)(ws);                 //  8,388,608 B  (16384 x 256 bf16)
    u16*   W1b = (u16*)(ws + 8388608);       //  1,048,576 B  ( 2048 x 256 bf16)
    u16*   Qt  = (u16*)(ws + 9437184);       //  2,097,152 B  ( 4096 x 256 bf16)
    u16*   Pt  = (u16*)(ws + 11534336);      //    262,144 B  ( 4096 x  32 bf16)
    float* S1  = (float*)(ws + 11796480);    //     32,768 B  (  256 x  32 f32)
    float* S2  = (float*)(ws + 11829248);    //     65,536 B  (  256 x  64 f32)

    cvt_bf16_kernel<<<4096, 256, 0, stream>>>(W0, W0b, 1048576);
    cvt_bf16_kernel<<<512, 256, 0, stream>>>(W1, W1b, 131072);
    build_qt_kernel<<<4096, 64, 0, stream>>>(x, emb, Qt);
    cin1_kernel<<<dim3(16, 64), 512, 0, stream>>>(W0b, Qt, b0, Pt, S1);
    cin2_kernel<<<dim3(16, 16), 512, 0, stream>>>(W1b, Qt, Pt, b1, S2);
    final_fc_kernel<<<1, 256, 0, stream>>>(S1, S2, fcW, fcb, out);
}

// Round 3
// 70.812 us; speedup vs baseline: 1.2810x; 1.2810x over previous
//
#include <hip/hip_runtime.h>

typedef unsigned short u16;
typedef short bf16x8 __attribute__((ext_vector_type(8)));
typedef float f32x4 __attribute__((ext_vector_type(4)));

#define AS1 __attribute__((address_space(1)))
#define AS3 __attribute__((address_space(3)))

__device__ __forceinline__ u16 f2bf(float f) {
    unsigned u = __float_as_uint(f);
    u += 0x7fffu + ((u >> 16) & 1u);   // RNE
    return (u16)(u >> 16);
}
__device__ __forceinline__ float bf2f(u16 h) {
    return __uint_as_float(((unsigned)h) << 16);
}

__device__ __forceinline__ void gload_lds16(const void* g, void* l) {
    __builtin_amdgcn_global_load_lds((AS1 unsigned int*)(g),
                                     (AS3 unsigned int*)(l), 16, 0, 0);
}

// ---------------- stage 1: dtype prep (merged W0+W1) ----------------
__global__ void cvt_bf16_kernel(const float* __restrict__ W0, const float* __restrict__ W1,
                                u16* __restrict__ W0b, u16* __restrict__ W1b) {
    int i = blockIdx.x * blockDim.x + threadIdx.x;
    const float* src; u16* dst; int j;
    if (i < 1048576) { src = W0; dst = W0b; j = i; }
    else             { src = W1; dst = W1b; j = i - 1048576; }
    float4 v = reinterpret_cast<const float4*>(src)[j];
    ushort4 o;
    o.x = f2bf(v.x); o.y = f2bf(v.y); o.z = f2bf(v.z); o.w = f2bf(v.w);
    reinterpret_cast<ushort4*>(dst)[j] = o;
}

// Qt[n][m] = x[b,m]*emb[m,d], n = b*16+d (4096 x 256 bf16)  + E1 fragment-packed copy
__global__ void build_qt_kernel(const float* __restrict__ x, const float* __restrict__ emb,
                                u16* __restrict__ Qt, u16* __restrict__ E1) {
    int n = blockIdx.x;           // 0..4095
    int b = n >> 4, d = n & 15;
    int m0 = threadIdx.x * 4;     // 64 threads * 4
    float4 xv = *reinterpret_cast<const float4*>(x + b * 256 + m0);
    ushort4 q;
    q.x = f2bf(xv.x * emb[(m0 + 0) * 16 + d]);
    q.y = f2bf(xv.y * emb[(m0 + 1) * 16 + d]);
    q.z = f2bf(xv.z * emb[(m0 + 2) * 16 + d]);
    q.w = f2bf(xv.w * emb[(m0 + 3) * 16 + d]);
    *reinterpret_cast<ushort4*>(Qt + n * 256 + m0) = q;
    // E1[(h=m0..m0+3, n)] in epilogue-fragment order: [ntile][wh][wn][f][g][lane][e]
    int e1 = (n >> 8) * 65536 + (m0 >> 7) * 32768 + ((n >> 6) & 3) * 8192
           + ((m0 >> 4) & 7) * 1024 + ((n >> 4) & 3) * 256
           + ((((m0 >> 2) & 3) << 4) + (n & 15)) * 4;
    *reinterpret_cast<ushort4*>(E1 + e1) = q;
}

// ---------------- stage 2: layer 1 (fused GEMM + h-reduction) ----------------
// 1-D grid 1024 blocks, 512 threads. Tile: 256 h x 256 n, K=256, BK=32, 4 LDS bufs,
// depth-3 prefetch with counted vmcnt (T3+T4). XCD-aware work permutation.
__global__ __launch_bounds__(512, 2) void cin1_kernel(
    const u16* __restrict__ W0b, const u16* __restrict__ Qt, const u16* __restrict__ E1,
    const float* __restrict__ b0, u16* __restrict__ E2, float* __restrict__ S1)
{
    __shared__ __attribute__((aligned(16))) u16 As[4][8192];
    __shared__ __attribute__((aligned(16))) u16 Bs[4][8192];
    __shared__ float part[2][256];

    const int tid = threadIdx.x, lane = tid & 63, w = tid >> 6;
    const int wh = w >> 2, wn = w & 3;
    // XCD swizzle: group g=lid&7 pins 16 o x 8 ntile (~4MB) to one XCD's L2
    const int lid = blockIdx.x;
    const int g8 = lid & 7, m = lid >> 3;
    const int o = ((g8 >> 1) << 4) | (m & 15);
    const int ntile = ((g8 & 1) << 3) | (m >> 4);

    // staging decode: LDS unit u = (w*2+i)*64 + L; sr=u>>3, q=u&7
    // inverse swizzle: r = 2*sr + (q&1); s = (q>>1) ^ (sr&3)
    const int dr = ((lane >> 3) << 1) | (lane & 1);
    const int dk = (((lane & 7) >> 1) ^ ((lane >> 3) & 3)) << 3;
    const u16* aSrc0 = W0b + (o * 256 + (w * 2 + 0) * 16 + dr) * 256 + dk;
    const u16* aSrc1 = W0b + (o * 256 + (w * 2 + 1) * 16 + dr) * 256 + dk;
    const u16* bSrc0 = Qt + (ntile * 256 + (w * 2 + 0) * 16 + dr) * 256 + dk;
    const u16* bSrc1 = Qt + (ntile * 256 + (w * 2 + 1) * 16 + dr) * 256 + dk;
    const int ldsA0 = (w * 2 + 0) * 512, ldsA1 = (w * 2 + 1) * 512;

    // fragment read: row r = fb + (lane&15), s = lane>>4; q = 2(s^((r>>1)&3)) + (r&1)
    const int l2 = (lane & 15) >> 1;
    const int qu = (((((lane >> 4) ^ (l2 & 3)) << 1) | (lane & 1)) << 3);
    const int aOff = wh * 4096 + l2 * 64 + qu;
    const int bOff = wn * 2048 + l2 * 64 + qu;

    f32x4 zero = {0.f, 0.f, 0.f, 0.f};
    f32x4 acc[8][4];
#pragma unroll
    for (int f = 0; f < 8; ++f)
#pragma unroll
        for (int gg = 0; gg < 4; ++gg) acc[f][gg] = zero;

    auto stage = [&](int kc, int bb) {
        int ko = kc * 32;
        gload_lds16(aSrc0 + ko, &As[bb][ldsA0]);
        gload_lds16(aSrc1 + ko, &As[bb][ldsA1]);
        gload_lds16(bSrc0 + ko, &Bs[bb][ldsA0]);
        gload_lds16(bSrc1 + ko, &Bs[bb][ldsA1]);
    };

    stage(0, 0); stage(1, 1); stage(2, 2);
#pragma unroll
    for (int kc = 0; kc < 8; ++kc) {
        if (kc < 6)       asm volatile("s_waitcnt vmcnt(8)" ::: "memory");
        else if (kc == 6) asm volatile("s_waitcnt vmcnt(4)" ::: "memory");
        else              asm volatile("s_waitcnt vmcnt(0)" ::: "memory");
        __builtin_amdgcn_s_barrier();
        asm volatile("" ::: "memory");
        const u16* Ab = &As[kc & 3][0];
        const u16* Bb = &Bs[kc & 3][0];
        bf16x8 a[8], b[4];
#pragma unroll
        for (int f = 0; f < 8; ++f)
            a[f] = *reinterpret_cast<const bf16x8*>(Ab + aOff + f * 512);
#pragma unroll
        for (int gg = 0; gg < 4; ++gg)
            b[gg] = *reinterpret_cast<const bf16x8*>(Bb + bOff + gg * 512);
#pragma unroll
        for (int f = 0; f < 8; ++f)
#pragma unroll
            for (int gg = 0; gg < 4; ++gg)
                acc[f][gg] = __builtin_amdgcn_mfma_f32_16x16x32_bf16(a[f], b[gg], acc[f][gg], 0, 0, 0);
        if (kc < 5) stage(kc + 3, (kc + 3) & 3);
    }

    // epilogue: X1[o][n] = sum_h Q[h][n] * G[h][n], weights pre-packed in E1 (coalesced)
    float psum[4] = {0.f, 0.f, 0.f, 0.f};
    const u16* eb = E1 + ntile * 65536 + wh * 32768 + wn * 8192 + lane * 4;
#pragma unroll
    for (int f = 0; f < 8; ++f)
#pragma unroll
        for (int gg = 0; gg < 4; ++gg) {
            ushort4 wv = *reinterpret_cast<const ushort4*>(eb + f * 1024 + gg * 256);
            psum[gg] += bf2f(wv.x) * acc[f][gg][0] + bf2f(wv.y) * acc[f][gg][1]
                      + bf2f(wv.z) * acc[f][gg][2] + bf2f(wv.w) * acc[f][gg][3];
        }
#pragma unroll
    for (int gg = 0; gg < 4; ++gg) {
        float p = psum[gg];
        p += __shfl_xor(p, 16);
        p += __shfl_xor(p, 32);
        if (lane < 16) part[wh][wn * 64 + gg * 16 + lane] = p;
    }
    __syncthreads();
    if (tid < 256) {
        const int nl = tid;
        float v = part[0][nl] + part[1][nl] + b0[o];
        float r = fmaxf(v, 0.0f);
        const int n = ntile * 256 + nl;
        if (o < 32) {
            // E2 fragment-packed: [ntile][f2][wn][g][lane][e]
            int idx = ntile * 8192 + (o >> 4) * 4096 + (nl >> 6) * 1024 + ((nl >> 4) & 3) * 256
                    + ((((o >> 2) & 3) << 4) + (nl & 15)) * 4 + (o & 3);
            E2[idx] = f2bf(r);
        } else {
            float s = r;                               // sum over d (nl&15)
            s += __shfl_xor(s, 1); s += __shfl_xor(s, 2);
            s += __shfl_xor(s, 4); s += __shfl_xor(s, 8);
            if ((nl & 15) == 0) S1[(n >> 4) * 32 + (o - 32)] = s;
        }
    }
}

// ---------------- stage 3: layer 2 ----------------
// 1-D grid 256 blocks, 512 threads. Tile: 128 rows (4 o x 32 h) x 256 n, BK=32, same pipeline.
__global__ __launch_bounds__(512, 2) void cin2_kernel(
    const u16* __restrict__ W1b, const u16* __restrict__ Qt, const u16* __restrict__ E2,
    const float* __restrict__ b1, float* __restrict__ S2)
{
    __shared__ __attribute__((aligned(16))) u16 As[4][4096];
    __shared__ __attribute__((aligned(16))) u16 Bs[4][8192];
    __shared__ float part[2][2][256];

    const int tid = threadIdx.x, lane = tid & 63, w = tid >> 6;
    const int wh = w >> 2, wn = w & 3;
    const int ntile = blockIdx.x & 15, og = blockIdx.x >> 4;

    const int dr = ((lane >> 3) << 1) | (lane & 1);
    const int dk = (((lane & 7) >> 1) ^ ((lane >> 3) & 3)) << 3;
    const u16* aSrc = W1b + (og * 128 + w * 16 + dr) * 256 + dk;          // 1 instr: 128 rows
    const u16* bSrc0 = Qt + (ntile * 256 + (w * 2 + 0) * 16 + dr) * 256 + dk;
    const u16* bSrc1 = Qt + (ntile * 256 + (w * 2 + 1) * 16 + dr) * 256 + dk;
    const int ldsA = w * 512;
    const int ldsB0 = (w * 2 + 0) * 512, ldsB1 = (w * 2 + 1) * 512;

    const int l2 = (lane & 15) >> 1;
    const int qu = (((((lane >> 4) ^ (l2 & 3)) << 1) | (lane & 1)) << 3);
    const int aOff = wh * 2048 + l2 * 64 + qu;
    const int bOff = wn * 2048 + l2 * 64 + qu;

    f32x4 zero = {0.f, 0.f, 0.f, 0.f};
    f32x4 acc[4][4];
#pragma unroll
    for (int f = 0; f < 4; ++f)
#pragma unroll
        for (int gg = 0; gg < 4; ++gg) acc[f][gg] = zero;

    auto stage = [&](int kc, int bb) {
        int ko = kc * 32;
        gload_lds16(aSrc + ko, &As[bb][ldsA]);
        gload_lds16(bSrc0 + ko, &Bs[bb][ldsB0]);
        gload_lds16(bSrc1 + ko, &Bs[bb][ldsB1]);
    };

    stage(0, 0); stage(1, 1); stage(2, 2);
#pragma unroll
    for (int kc = 0; kc < 8; ++kc) {
        if (kc < 6)       asm volatile("s_waitcnt vmcnt(6)" ::: "memory");
        else if (kc == 6) asm volatile("s_waitcnt vmcnt(3)" ::: "memory");
        else              asm volatile("s_waitcnt vmcnt(0)" ::: "memory");
        __builtin_amdgcn_s_barrier();
        asm volatile("" ::: "memory");
        const u16* Ab = &As[kc & 3][0];
        const u16* Bb = &Bs[kc & 3][0];
        bf16x8 a[4], b[4];
#pragma unroll
        for (int f = 0; f < 4; ++f)
            a[f] = *reinterpret_cast<const bf16x8*>(Ab + aOff + f * 512);
#pragma unroll
        for (int gg = 0; gg < 4; ++gg)
            b[gg] = *reinterpret_cast<const bf16x8*>(Bb + bOff + gg * 512);
#pragma unroll
        for (int f = 0; f < 4; ++f)
#pragma unroll
            for (int gg = 0; gg < 4; ++gg)
                acc[f][gg] = __builtin_amdgcn_mfma_f32_16x16x32_bf16(a[f], b[gg], acc[f][gg], 0, 0, 0);
        if (kc < 5) stage(kc + 3, (kc + 3) & 3);
    }

    // reduction: h = (f&1)*16 + 4*(lane>>4) + e; o_local = 2*wh + (f>>1)
    float psum[2][4] = {{0.f,0.f,0.f,0.f},{0.f,0.f,0.f,0.f}};
    const u16* eb = E2 + ntile * 8192 + wn * 1024 + lane * 4;
#pragma unroll
    for (int f = 0; f < 4; ++f)
#pragma unroll
        for (int gg = 0; gg < 4; ++gg) {
            ushort4 wv = *reinterpret_cast<const ushort4*>(eb + (f & 1) * 4096 + gg * 256);
            psum[f >> 1][gg] += bf2f(wv.x) * acc[f][gg][0] + bf2f(wv.y) * acc[f][gg][1]
                              + bf2f(wv.z) * acc[f][gg][2] + bf2f(wv.w) * acc[f][gg][3];
        }
#pragma unroll
    for (int ol = 0; ol < 2; ++ol)
#pragma unroll
        for (int gg = 0; gg < 4; ++gg) {
            float p = psum[ol][gg];
            p += __shfl_xor(p, 16);
            p += __shfl_xor(p, 32);
            if (lane < 16) part[wh][ol][wn * 64 + gg * 16 + lane] = p;
        }
    __syncthreads();
    if (tid < 256) {
        const int nl = tid;
        const int n = ntile * 256 + nl;
#pragma unroll
        for (int ol4 = 0; ol4 < 4; ++ol4) {
            const int oo = og * 4 + ol4;
            float v = part[ol4 >> 1][ol4 & 1][nl] + b1[oo];
            float r = fmaxf(v, 0.0f);
            float s = r;
            s += __shfl_xor(s, 1); s += __shfl_xor(s, 2);
            s += __shfl_xor(s, 4); s += __shfl_xor(s, 8);
            if ((nl & 15) == 0) S2[(n >> 4) * 64 + oo] = s;
        }
    }
}

// ---------------- stage 4: final FC ----------------
__global__ void final_fc_kernel(const float* __restrict__ S1, const float* __restrict__ S2,
                                const float* __restrict__ fcW, const float* __restrict__ fcb,
                                float* __restrict__ out) {
    int b = threadIdx.x;   // 256
    float a0 = fcb[0], a1 = fcb[1];
#pragma unroll 8
    for (int c = 0; c < 32; ++c) {
        float v = S1[b * 32 + c];
        a0 += v * fcW[c]; a1 += v * fcW[96 + c];
    }
#pragma unroll 8
    for (int c = 0; c < 64; ++c) {
        float v = S2[b * 64 + c];
        a0 += v * fcW[32 + c]; a1 += v * fcW[96 + 32 + c];
    }
    out[b * 2 + 0] = a0;
    out[b * 2 + 1] = a1;
}

extern "C" void kernel_launch(void* const* d_in, const int* in_sizes, int n_in,
                              void* d_out, int out_size, void* d_ws, size_t ws_size,
                              hipStream_t stream) {
    const float* x   = (const float*)d_in[0];
    const float* emb = (const float*)d_in[1];
    const float* W0  = (const float*)d_in[2];
    const float* b0  = (const float*)d_in[3];
    const float* W1  = (const float*)d_in[4];
    const float* b1  = (const float*)d_in[5];
    const float* fcW = (const float*)d_in[6];
    const float* fcb = (const float*)d_in[7];
    float* out = (float*)d_out;

    char* ws = (char*)d_ws;
    u16*   W0b = (u16*)(ws);                 //  8,388,608 B  (16384 x 256 bf16)
    u16*   W1b = (u16*)(ws + 8388608);       //  1,048,576 B  ( 2048 x 256 bf16)
    u16*   Qt  = (u16*)(ws + 9437184);       //  2,097,152 B  ( 4096 x 256 bf16)
    u16*   E1  = (u16*)(ws + 11534336);      //  2,097,152 B  (frag-packed Q weights)
    u16*   E2  = (u16*)(ws + 13631488);      //    262,144 B  (frag-packed relu(X1[:,:32]))
    float* S1  = (float*)(ws + 13893632);    //     32,768 B  (  256 x  32 f32)
    float* S2  = (float*)(ws + 13926400);    //     65,536 B  (  256 x  64 f32)

    cvt_bf16_kernel<<<4608, 256, 0, stream>>>(W0, W1, W0b, W1b);
    build_qt_kernel<<<4096, 64, 0, stream>>>(x, emb, Qt, E1);
    cin1_kernel<<<1024, 512, 0, stream>>>(W0b, Qt, E1, b0, E2, S1);
    cin2_kernel<<<256, 512, 0, stream>>>(W1b, Qt, E2, b1, S2);
    final_fc_kernel<<<1, 256, 0, stream>>>(S1, S2, fcW, fcb, out);
}